// Round 10
// baseline (1725.092 us; speedup 1.0000x reference)
//
#include <hip/hip_runtime.h>
#include <math.h>

#define NIN 64
#define NHID 128
#define NOUT 64

typedef __bf16 bf16x8 __attribute__((ext_vector_type(8)));
typedef float  floatx4 __attribute__((ext_vector_type(4)));

// branch-free fast transcendentals (v_exp_f32 + v_rcp_f32 path).
__device__ __forceinline__ float fsig(float x){
  return __fdividef(1.0f, 1.0f + __expf(-x));
}
__device__ __forceinline__ float ftanh(float x){
  return 1.0f - 2.0f*__fdividef(1.0f, 1.0f + __expf(2.0f*x));
}
__device__ __forceinline__ float b2f_lo(unsigned p){ unsigned b = p<<16; return __uint_as_float(b); }
__device__ __forceinline__ float b2f_hi(unsigned p){ unsigned b = p & 0xffff0000u; return __uint_as_float(b); }
__device__ __forceinline__ unsigned f2pk(float lo, float hi){
  __bf16 a=(__bf16)lo, b=(__bf16)hi;
  unsigned short ua, ub;
  __builtin_memcpy(&ua,&a,2); __builtin_memcpy(&ub,&b,2);
  return (unsigned)ua | ((unsigned)ub<<16);
}

// ---------------- precompute: degree, dinv, CSR ----------------
__global__ void k_deg_init(int* __restrict__ deg, int n){
  int v = blockIdx.x*256 + threadIdx.x;
  if(v<n) deg[v] = 1;
}
__global__ void k_deg_count(const int* __restrict__ dst, int E, int* __restrict__ deg){
  int e = blockIdx.x*256 + threadIdx.x;
  if(e<E) atomicAdd(&deg[dst[e]], 1);
}
__global__ void k_dinv(const int* __restrict__ deg, float* __restrict__ dinv, int n){
  int v = blockIdx.x*256 + threadIdx.x;
  if(v<n) dinv[v] = rsqrtf((float)deg[v]);
}
// single-pass scan: per-thread serial chunk + ONE 1024-wide block scan
__global__ __launch_bounds__(1024) void k_scan(const int* __restrict__ deg,
    int* __restrict__ row_ptr, int* __restrict__ fill, int n){
  __shared__ int lds[1024];
  const int t = threadIdx.x;
  const int per = (n + 1023)/1024;
  int a = t*per, b = a+per; if(b>n) b=n;
  int local=0;
  for(int v=a; v<b; ++v) local += deg[v]-1;
  lds[t]=local;
  __syncthreads();
  for(int off=1; off<1024; off<<=1){
    int x=(t>=off)? lds[t-off]:0;
    __syncthreads();
    lds[t]+=x;
    __syncthreads();
  }
  int run = lds[t]-local;          // exclusive prefix of this chunk
  for(int v=a; v<b; ++v){
    row_ptr[v]=run; fill[v]=run;
    run += deg[v]-1;
  }
  if(t==1023) row_ptr[n]=lds[1023];
}
__global__ void k_fill(const int* __restrict__ src, const int* __restrict__ dst, int E,
                       int* __restrict__ fill, int* __restrict__ ecol){
  int e = blockIdx.x*256 + threadIdx.x;
  if(e<E){
    int d = dst[e];
    int pos = atomicAdd(&fill[d], 1);
    ecol[pos] = src[e];
  }
}

// ---- one-time ELL build: step-invariant gather metadata, hoisted out of ----
// the 64-step loop. ell[(tile*8+wv)*64+kk] = {col(node 2wv,kk), col(2wv+1,kk)}
// padded to ghost row NP; kinfo[tile*8+wv] = cappedK | (ovf<<8).
__global__ __launch_bounds__(64) void k_ell(const int* __restrict__ row_ptr,
    const int* __restrict__ ecol, int2* __restrict__ ell, int* __restrict__ kinfo,
    int n, int NP){
  int tw = blockIdx.x;              // tile*8 + wv
  int kk = threadIdx.x;             // 0..63
  int vA = (tw>>3)*16 + 2*(tw&7);
  int vB = vA+1;
  int begA=0,dA=0,begB=0,dB=0;
  if(vA<n){ begA=row_ptr[vA]; dA=row_ptr[vA+1]-begA; }
  if(vB<n){ begB=row_ptr[vB]; dB=row_ptr[vB+1]-begB; }
  int cA = (kk<dA)? ecol[begA+kk] : NP;
  int cB = (kk<dB)? ecol[begB+kk] : NP;
  ell[(size_t)tw*64+kk] = make_int2(cA,cB);
  if(kk==0){
    int a=dA>64?64:dA, b=dB>64?64:dB;
    int K=a>b?a:b;
    kinfo[tw]=K | (((dA>64||dB>64)?1:0)<<8);
  }
}

// ---------------- weight prep ----------------
__global__ void k_prep_wb(const float* __restrict__ Wi, const float* __restrict__ Wf,
                          const float* __restrict__ Wo, const float* __restrict__ Wg,
                          __bf16* __restrict__ Wb){
  int idx = blockIdx.x*256 + threadIdx.x;
  if(idx >= 32*6*64*8) return;
  int jj = idx & 7;
  int L  = (idx >> 3) & 63;
  int t  = idx >> 9;
  int kt = t - (t/6)*6, CT = t/6;
  int colj = CT*16 + (L & 15);
  int k    = kt*32 + ((L >> 4) << 3) + jj;
  int gate = colj >> 7, jg = colj & 127;
  const float* W = (gate==0)? Wi : (gate==1)? Wf : (gate==2)? Wo : Wg;
  Wb[idx] = (__bf16)W[jg*192 + k];
}
__global__ void k_prep_w1(const float* __restrict__ W1, float* __restrict__ W1t){
  int idx = blockIdx.x*256 + threadIdx.x;
  if(idx >= 128*256) return;
  int k = idx >> 8, j = idx & 255;
  W1t[idx] = (j<128)? W1[j*256+k] : W1[(j-128)*256+128+k];
}
__global__ void k_prep_wc(const float* __restrict__ Wc, float* __restrict__ Wct){
  int idx = blockIdx.x*256 + threadIdx.x;
  if(idx >= 128*64) return;
  int k = idx/64, j = idx%64;
  Wct[idx] = Wc[j*128+k];
}

// ------- init: zero h (both bufs incl ghost row), c, xs ghost rows --------
__global__ void k_init(unsigned* __restrict__ hpA, unsigned* __restrict__ hpB,
                       float* __restrict__ cbuf, __bf16* __restrict__ xs,
                       int NP, int T){
  int i = blockIdx.x*256 + threadIdx.x;
  if(i < (NP+1)*64){ hpA[i]=0u; hpB[i]=0u; }
  if(i < NP*128) cbuf[i]=0.f;
  if(i < T*64){ int t=i>>6, f=i&63; xs[((size_t)t*(NP+1) + NP)*64 + f] = (__bf16)0.f; }
}

// ---------------- xs = dinv[v] * x, bf16, layout [T][NP+1][64] ------------
// vectorized: 1 thread = 8 elems (32B load, 16B store)  [R1-verified]
__global__ void k_xscale(const float* __restrict__ x, const float* __restrict__ dinv,
                         __bf16* __restrict__ xs, int n, int NP){
  int i = blockIdx.x*256 + threadIdx.x;      // index of 8-float group
  if(i >= n*8) return;
  int t = blockIdx.y;
  float dv = dinv[i>>3];
  const float4* xp = (const float4*)(x + (size_t)t*(size_t)n*64) + (size_t)i*2;
  float4 a = xp[0], b = xp[1];
  bf16x8 o;
  o[0]=(__bf16)(a.x*dv); o[1]=(__bf16)(a.y*dv); o[2]=(__bf16)(a.z*dv); o[3]=(__bf16)(a.w*dv);
  o[4]=(__bf16)(b.x*dv); o[5]=(__bf16)(b.y*dv); o[6]=(__bf16)(b.z*dv); o[7]=(__bf16)(b.w*dv);
  *(bf16x8*)(xs + ((size_t)t*(NP+1))*64 + (size_t)i*8) = o;
}

// ---------------- fused step: R0 inner body, step-invariant staging removed.
// Per step now: gather straight from precomputed ELL (wave-uniform int2
// loads), ONE __syncthreads (s_a write -> af read), MFMA, pointwise.
__global__ __launch_bounds__(512,5) void k_step(
    const __bf16* __restrict__ xst,        // [NP+1][64] slab for step t
    const unsigned* __restrict__ hp_prev,  // [NP+1][64]
    unsigned* __restrict__ hp_cur,
    float* __restrict__ cbuf,              // [NP][128]
    float* __restrict__ hbuf,              // [NP][128] (written on last step)
    const int* __restrict__ row_ptr, const int* __restrict__ ecol,
    const float* __restrict__ dinv,
    const int2* __restrict__ ell, const int* __restrict__ kinfo,
    const __bf16* __restrict__ Wb,
    const float* __restrict__ bi, const float* __restrict__ bf_,
    const float* __restrict__ bo, const float* __restrict__ bg,
    int n, int NP, int last)
{
  __shared__ __align__(16) __bf16 s_a[6*544];
  const int tid=threadIdx.x, wv=tid>>6, l=tid&63;
  const int l15=l&15, quad=l>>4;
  const int v0=blockIdx.x*16;
  const int tw=blockIdx.x*8+wv;

  // ---- phase 1: gather (self + ELL neighbors), 2 nodes per wave ----
  const int ki=kinfo[tw];
  const int K=ki&255;
  float ax[2], alo[2], ahi[2];
  #pragma unroll
  for(int i=0;i<2;++i){
    int v=v0+2*wv+i;
    ax[i]=(float)xst[(size_t)v*64+l];
    unsigned p=hp_prev[(size_t)v*64+l];
    alo[i]=b2f_lo(p); ahi[i]=b2f_hi(p);
  }
  const int2* er=ell + (size_t)tw*64;
  #pragma unroll 2
  for(int kk=0;kk<K;++kk){
    int2 u=er[kk];
    float    x0=(float)xst[(size_t)u.x*64+l];
    unsigned p0=hp_prev[(size_t)u.x*64+l];
    float    x1=(float)xst[(size_t)u.y*64+l];
    unsigned p1=hp_prev[(size_t)u.y*64+l];
    ax[0]+=x0; alo[0]+=b2f_lo(p0); ahi[0]+=b2f_hi(p0);
    ax[1]+=x1; alo[1]+=b2f_lo(p1); ahi[1]+=b2f_hi(p1);
  }
  if(ki>>8){                       // rare deg>64 overflow via CSR
    #pragma unroll
    for(int i=0;i<2;++i){
      int v=v0+2*wv+i;
      if(v<n){
        int beg=row_ptr[v], end=row_ptr[v+1];
        if(end-beg>64){
          for(int e2=beg+64;e2<end;++e2){
            int u=ecol[e2];
            ax[i]+=(float)xst[(size_t)u*64+l];
            unsigned p=hp_prev[(size_t)u*64+l];
            alo[i]+=b2f_lo(p); ahi[i]+=b2f_hi(p);
          }
        }
      }
    }
  }
  {
    int kt0=l>>5, q0=(l>>3)&3, j0=l&7;
    int L2=2*l, kt1=2+(L2>>5), q1=(L2>>3)&3, j1=L2&7;
    #pragma unroll
    for(int i=0;i<2;++i){
      int v=v0+2*wv+i;
      float dv=(v<n)? dinv[v] : 0.f;
      int m=2*wv+i;
      s_a[kt0*544+q0*136+m*8+j0]=(__bf16)(dv*ax[i]);
      *(unsigned*)&s_a[kt1*544+q1*136+m*8+j1]=f2pk(dv*alo[i],dv*ahi[i]);
    }
  }
  __syncthreads();                 // the ONLY barrier in the kernel

  // ---- phase 2: MFMA; wave wv: CT = 8g+wv per gate g ----
  bf16x8 af[6];
  #pragma unroll
  for(int kt=0;kt<6;++kt)
    af[kt]=*(bf16x8*)&s_a[kt*544+quad*136+l15*8];
  const int jg=16*wv+l15;
  floatx4 acc[4];
  {
    #pragma unroll
    for(int g=0;g<4;++g){
      const float* bsel = (g==0)? bi : (g==1)? bf_ : (g==2)? bo : bg;
      float b=bsel[jg];
      floatx4 a={b,b,b,b};
      const __bf16* bp=Wb + (size_t)((8*g+wv)*6)*512 + (size_t)l*8;
      #pragma unroll
      for(int kt=0;kt<6;++kt)
        a=__builtin_amdgcn_mfma_f32_16x16x32_bf16(af[kt],*(const bf16x8*)(bp+kt*512),a,0,0,0);
      acc[g]=a;
    }
  }

  // ---- phase 3: LSTM pointwise in registers (fast transcendentals) ----
  #pragma unroll
  for(int r=0;r<4;++r){
    int m=quad*4+r, v=v0+m;
    float I=fsig (acc[0][r]);
    float F=fsig (acc[1][r]);
    float O=fsig (acc[2][r]);
    float G=ftanh(acc[3][r]);
    size_t coff=(size_t)v*128+jg;
    float cn=F*cbuf[coff]+I*G;
    cbuf[coff]=cn;
    float hn=O*ftanh(cn);
    float dv=(v<n)? dinv[v] : 0.f;
    float hs=dv*hn;
    float hs2=__shfl_xor(hs,1,64);
    if((l15&1)==0)
      hp_cur[(size_t)v*64+(jg>>1)]=f2pk(hs,hs2);   // word w = cols {2w,2w+1}
    if(last) hbuf[coff]=hn;
  }
}

// ---------------- head (verified chain) ----------------
__global__ __launch_bounds__(256) void k_head1(const float* __restrict__ h,
    const float* __restrict__ W1t, float* __restrict__ Hio, int n){
  __shared__ float s_h[16][NHID];
  int v0 = blockIdx.x*16;
  for(int i=threadIdx.x; i<16*NHID; i+=256){
    int m = i/NHID, k = i - m*NHID;
    int v = v0 + m;
    s_h[m][k] = (v<n)? h[(size_t)v*NHID + k] : 0.0f;
  }
  __syncthreads();
  int j = threadIdx.x;
  float acc[16];
  #pragma unroll
  for(int m=0;m<16;++m) acc[m]=0.f;
  for(int k=0;k<NHID;++k){
    float w = W1t[k*256 + j];
    #pragma unroll
    for(int m=0;m<16;++m) acc[m] = fmaf(w, s_h[m][k], acc[m]);
  }
  for(int m=0;m<16;++m){
    int v = v0 + m;
    if(v >= n) break;
    Hio[(size_t)v*256 + j] = acc[m];
  }
}
__global__ __launch_bounds__(256) void k_e2n(const float* __restrict__ Hio,
    const int* __restrict__ row_ptr, const int* __restrict__ col,
    const float* __restrict__ b1, float* __restrict__ nodes, int n){
  int wv = threadIdx.x >> 6, lane = threadIdx.x & 63;
  int v = blockIdx.x*4 + wv;
  if(v >= n) return;
  float base0 = Hio[(size_t)v*256 + lane]      + b1[lane];
  float base1 = Hio[(size_t)v*256 + 64 + lane] + b1[64+lane];
  float a0=0.f, a1=0.f;
  int beg=row_ptr[v], end=row_ptr[v+1];
  int e=beg;
  for(; e+1<end; e+=2){          // 2-way unroll: double the loads in flight
    int u0 = col[e], u1 = col[e+1];
    float p0 = Hio[(size_t)u0*256 + 128 + lane];
    float q0 = Hio[(size_t)u0*256 + 192 + lane];
    float p1 = Hio[(size_t)u1*256 + 128 + lane];
    float q1 = Hio[(size_t)u1*256 + 192 + lane];
    a0 += fmaxf(base0 + p0, 0.0f) + fmaxf(base0 + p1, 0.0f);
    a1 += fmaxf(base1 + q0, 0.0f) + fmaxf(base1 + q1, 0.0f);
  }
  if(e<end){
    int u = col[e];
    a0 += fmaxf(base0 + Hio[(size_t)u*256 + 128 + lane], 0.0f);
    a1 += fmaxf(base1 + Hio[(size_t)u*256 + 192 + lane], 0.0f);
  }
  nodes[(size_t)v*NHID + lane]      = a0;
  nodes[(size_t)v*NHID + 64 + lane] = a1;
}
__global__ __launch_bounds__(64) void k_head2(const float* __restrict__ nodes,
    const float* __restrict__ Wct, float* __restrict__ tmp, int n){
  __shared__ float s_n[16][NHID];
  int v0 = blockIdx.x*16;
  for(int i=threadIdx.x; i<16*NHID; i+=64){
    int m = i/NHID, k = i - m*NHID;
    int v = v0 + m;
    s_n[m][k] = (v<n)? nodes[(size_t)v*NHID + k] : 0.0f;
  }
  __syncthreads();
  int j = threadIdx.x;
  float acc[16];
  #pragma unroll
  for(int m=0;m<16;++m) acc[m]=0.f;
  for(int k=0;k<NHID;++k){
    float w = Wct[k*64 + j];
    #pragma unroll
    for(int m=0;m<16;++m) acc[m] = fmaf(w, s_n[m][k], acc[m]);
  }
  for(int m=0;m<16;++m){
    int v = v0 + m;
    if(v >= n) break;
    tmp[(size_t)v*64 + j] = acc[m];
  }
}
__global__ __launch_bounds__(256) void k_final(const float* __restrict__ tmp,
    const int* __restrict__ row_ptr, const int* __restrict__ col,
    const float* __restrict__ dinv, const float* __restrict__ bc,
    float* __restrict__ out, int n){
  int wv = threadIdx.x >> 6, lane = threadIdx.x & 63;
  int v = blockIdx.x*4 + wv;
  if(v >= n) return;
  float dv = dinv[v];
  float acc = dv*dv*tmp[(size_t)v*64 + lane];
  int beg=row_ptr[v], end=row_ptr[v+1];
  int e=beg;
  for(; e+1<end; e+=2){          // 2-way unroll
    int u0 = col[e], u1 = col[e+1];
    float d0 = dinv[u0], d1 = dinv[u1];
    float t0 = tmp[(size_t)u0*64 + lane];
    float t1 = tmp[(size_t)u1*64 + lane];
    acc = fmaf(dv*d0, t0, acc);
    acc = fmaf(dv*d1, t1, acc);
  }
  if(e<end){
    int u = col[e];
    acc = fmaf(dv*dinv[u], tmp[(size_t)u*64 + lane], acc);
  }
  out[(size_t)v*64 + lane] = acc + bc[lane];
}

extern "C" void kernel_launch(void* const* d_in, const int* in_sizes, int n_in,
                              void* d_out, int out_size, void* d_ws, size_t ws_size,
                              hipStream_t stream) {
  (void)n_in; (void)ws_size;
  const float* x  = (const float*)d_in[0];
  const int*   ei = (const int*)d_in[1];
  const float* Wi = (const float*)d_in[4];  const float* bi  = (const float*)d_in[5];
  const float* Wf = (const float*)d_in[6];  const float* bf_ = (const float*)d_in[7];
  const float* Wo = (const float*)d_in[8];  const float* bo  = (const float*)d_in[9];
  const float* Wg = (const float*)d_in[10]; const float* bg  = (const float*)d_in[11];
  const float* W1 = (const float*)d_in[12]; const float* b1  = (const float*)d_in[13];
  const float* Wc = (const float*)d_in[14]; const float* bc  = (const float*)d_in[15];
  float* out = (float*)d_out;

  const int E = in_sizes[2];
  const int n = out_size / NOUT;
  const int T = in_sizes[0] / (n * NIN);
  const int ntiles = (n + 15)/16;
  const int NP = ntiles*16;
  const int* srcl = ei;
  const int* dstl = ei + E;

  char* p = (char*)d_ws;
  auto alloc = [&](size_t bytes){ char* r = p; p += ((bytes + 255)/256)*256; return r; };
  int*      deg     = (int*)     alloc((size_t)n*4);
  float*    dinv    = (float*)   alloc((size_t)n*4);
  int*      row_ptr = (int*)     alloc((size_t)(n+1)*4);
  int*      fill    = (int*)     alloc((size_t)n*4);
  int*      ecol    = (int*)     alloc((size_t)E*4);
  int2*     ell     = (int2*)    alloc((size_t)ntiles*8*64*8);
  int*      kinfo   = (int*)     alloc((size_t)ntiles*8*4);
  __bf16*   Wb      = (__bf16*)  alloc((size_t)32*6*64*8*2);
  float*    W1t     = (float*)   alloc((size_t)128*256*4);
  float*    Wct     = (float*)   alloc((size_t)128*64*4);
  __bf16*   xs      = (__bf16*)  alloc((size_t)T*(NP+1)*64*2);
  unsigned* hpA     = (unsigned*)alloc((size_t)(NP+1)*64*4);
  unsigned* hpB     = (unsigned*)alloc((size_t)(NP+1)*64*4);
  float*    cbuf    = (float*)   alloc((size_t)NP*128*4);
  float*    hbuf    = (float*)   alloc((size_t)NP*128*4);
  float*    Hio     = (float*)   alloc((size_t)NP*256*4);
  float*    nodes   = (float*)   alloc((size_t)n*NHID*4);
  float*    tmp     = (float*)   alloc((size_t)NP*64*4);

  int gn = (n+255)/256;
  int gE = (E+255)/256;

  k_deg_init <<<gn, 256, 0, stream>>>(deg, n);
  k_deg_count<<<gE, 256, 0, stream>>>(dstl, E, deg);
  k_dinv     <<<gn, 256, 0, stream>>>(deg, dinv, n);
  k_scan     <<<1, 1024, 0, stream>>>(deg, row_ptr, fill, n);
  k_fill     <<<gE, 256, 0, stream>>>(srcl, dstl, E, fill, ecol);
  k_ell      <<<ntiles*8, 64, 0, stream>>>(row_ptr, ecol, ell, kinfo, n, NP);

  k_prep_wb<<<(32*6*64*8+255)/256, 256, 0, stream>>>(Wi, Wf, Wo, Wg, Wb);
  k_prep_w1<<<(128*256+255)/256, 256, 0, stream>>>(W1, W1t);
  k_prep_wc<<<(128*64+255)/256, 256, 0, stream>>>(Wc, Wct);

  k_init<<<((NP*128)+255)/256, 256, 0, stream>>>(hpA, hpB, cbuf, xs, NP, T);
  k_xscale<<<dim3((n*8+255)/256, T), 256, 0, stream>>>(x, dinv, xs, n, NP);

  for(int t=0; t<T; ++t){
    const __bf16* xst = xs + (size_t)t*(size_t)(NP+1)*64;
    const unsigned* hp = (t & 1)? hpB : hpA;
    unsigned*       hc = (t & 1)? hpA : hpB;
    k_step<<<ntiles, 512, 0, stream>>>(xst, hp, hc, cbuf, hbuf, row_ptr, ecol, dinv,
                                       ell, kinfo, Wb, bi, bf_, bo, bg, n, NP,
                                       (t==T-1)?1:0);
  }

  k_head1<<<ntiles, 256, 0, stream>>>(hbuf, W1t, Hio, n);
  k_e2n  <<<(n+3)/4, 256, 0, stream>>>(Hio, row_ptr, ecol, b1, nodes, n);
  k_head2<<<(n+15)/16, 64, 0, stream>>>(nodes, Wct, tmp, n);
  k_final<<<(n+3)/4, 256, 0, stream>>>(tmp, row_ptr, ecol, dinv, bc, out, n);
}

// Round 11
// 1535.608 us; speedup vs baseline: 1.1234x; 1.1234x over previous
//
#include <hip/hip_runtime.h>
#include <math.h>

#define NIN 64
#define NHID 128
#define NOUT 64

typedef __bf16 bf16x8 __attribute__((ext_vector_type(8)));
typedef float  floatx4 __attribute__((ext_vector_type(4)));

// branch-free fast transcendentals (v_exp_f32 + v_rcp_f32 path).
__device__ __forceinline__ float fsig(float x){
  return __fdividef(1.0f, 1.0f + __expf(-x));
}
__device__ __forceinline__ float ftanh(float x){
  return 1.0f - 2.0f*__fdividef(1.0f, 1.0f + __expf(2.0f*x));
}
__device__ __forceinline__ float b2f_lo(unsigned p){ unsigned b = p<<16; return __uint_as_float(b); }
__device__ __forceinline__ float b2f_hi(unsigned p){ unsigned b = p & 0xffff0000u; return __uint_as_float(b); }
__device__ __forceinline__ unsigned f2pk(float lo, float hi){
  __bf16 a=(__bf16)lo, b=(__bf16)hi;
  unsigned short ua, ub;
  __builtin_memcpy(&ua,&a,2); __builtin_memcpy(&ub,&b,2);
  return (unsigned)ua | ((unsigned)ub<<16);
}

// ---------------- precompute: degree, dinv, CSR ----------------
__global__ void k_deg_init(int* __restrict__ deg, int n){
  int v = blockIdx.x*256 + threadIdx.x;
  if(v<n) deg[v] = 1;
}
__global__ void k_deg_count(const int* __restrict__ dst, int E, int* __restrict__ deg){
  int e = blockIdx.x*256 + threadIdx.x;
  if(e<E) atomicAdd(&deg[dst[e]], 1);
}
__global__ void k_dinv(const int* __restrict__ deg, float* __restrict__ dinv, int n){
  int v = blockIdx.x*256 + threadIdx.x;
  if(v<n) dinv[v] = rsqrtf((float)deg[v]);
}
// single-pass scan: per-thread serial chunk + ONE 1024-wide block scan
__global__ __launch_bounds__(1024) void k_scan(const int* __restrict__ deg,
    int* __restrict__ row_ptr, int* __restrict__ fill, int n){
  __shared__ int lds[1024];
  const int t = threadIdx.x;
  const int per = (n + 1023)/1024;
  int a = t*per, b = a+per; if(b>n) b=n;
  int local=0;
  for(int v=a; v<b; ++v) local += deg[v]-1;
  lds[t]=local;
  __syncthreads();
  for(int off=1; off<1024; off<<=1){
    int x=(t>=off)? lds[t-off]:0;
    __syncthreads();
    lds[t]+=x;
    __syncthreads();
  }
  int run = lds[t]-local;          // exclusive prefix of this chunk
  for(int v=a; v<b; ++v){
    row_ptr[v]=run; fill[v]=run;
    run += deg[v]-1;
  }
  if(t==1023) row_ptr[n]=lds[1023];
}
__global__ void k_fill(const int* __restrict__ src, const int* __restrict__ dst, int E,
                       int* __restrict__ fill, int* __restrict__ ecol){
  int e = blockIdx.x*256 + threadIdx.x;
  if(e<E){
    int d = dst[e];
    int pos = atomicAdd(&fill[d], 1);
    ecol[pos] = src[e];
  }
}

// ---------------- weight prep ----------------
__global__ void k_prep_wb(const float* __restrict__ Wi, const float* __restrict__ Wf,
                          const float* __restrict__ Wo, const float* __restrict__ Wg,
                          __bf16* __restrict__ Wb){
  int idx = blockIdx.x*256 + threadIdx.x;
  if(idx >= 32*6*64*8) return;
  int jj = idx & 7;
  int L  = (idx >> 3) & 63;
  int t  = idx >> 9;
  int kt = t - (t/6)*6, CT = t/6;
  int colj = CT*16 + (L & 15);
  int k    = kt*32 + ((L >> 4) << 3) + jj;
  int gate = colj >> 7, jg = colj & 127;
  const float* W = (gate==0)? Wi : (gate==1)? Wf : (gate==2)? Wo : Wg;
  Wb[idx] = (__bf16)W[jg*192 + k];
}
__global__ void k_prep_w1(const float* __restrict__ W1, float* __restrict__ W1t){
  int idx = blockIdx.x*256 + threadIdx.x;
  if(idx >= 128*256) return;
  int k = idx >> 8, j = idx & 255;
  W1t[idx] = (j<128)? W1[j*256+k] : W1[(j-128)*256+128+k];
}
__global__ void k_prep_wc(const float* __restrict__ Wc, float* __restrict__ Wct){
  int idx = blockIdx.x*256 + threadIdx.x;
  if(idx >= 128*64) return;
  int k = idx/64, j = idx%64;
  Wct[idx] = Wc[j*128+k];
}

// ------- init: zero h (both bufs incl ghost row), packed c, xs ghost rows --
__global__ void k_init(unsigned* __restrict__ hpA, unsigned* __restrict__ hpB,
                       unsigned* __restrict__ cbufp, __bf16* __restrict__ xs,
                       int NP, int T){
  int i = blockIdx.x*256 + threadIdx.x;
  if(i < (NP+1)*64){ hpA[i]=0u; hpB[i]=0u; }
  if(i < NP*64) cbufp[i]=0u;
  if(i < T*64){ int t=i>>6, f=i&63; xs[((size_t)t*(NP+1) + NP)*64 + f] = (__bf16)0.f; }
}

// ---------------- xs = dinv[v] * x, bf16, layout [T][NP+1][64] ------------
// vectorized: 1 thread = 8 elems (32B load, 16B store)  [R1-verified]
__global__ void k_xscale(const float* __restrict__ x, const float* __restrict__ dinv,
                         __bf16* __restrict__ xs, int n, int NP){
  int i = blockIdx.x*256 + threadIdx.x;      // index of 8-float group
  if(i >= n*8) return;
  int t = blockIdx.y;
  float dv = dinv[i>>3];
  const float4* xp = (const float4*)(x + (size_t)t*(size_t)n*64) + (size_t)i*2;
  float4 a = xp[0], b = xp[1];
  bf16x8 o;
  o[0]=(__bf16)(a.x*dv); o[1]=(__bf16)(a.y*dv); o[2]=(__bf16)(a.z*dv); o[3]=(__bf16)(a.w*dv);
  o[4]=(__bf16)(b.x*dv); o[5]=(__bf16)(b.y*dv); o[6]=(__bf16)(b.z*dv); o[7]=(__bf16)(b.w*dv);
  *(bf16x8*)(xs + ((size_t)t*(NP+1))*64 + (size_t)i*8) = o;
}

// ---------------- fused step: R8-proven structure (625 blocks x 512 thr, ----
// 8 waves, 16 nodes/block, 2 nodes/wave gather, CT=8g+wv MFMA mapping).
// R11 confined changes: gather unroll 2->4 (2x loads in flight, latency
// bound); cbuf packed bf16x2 (halves c traffic + L2 footprint).
__global__ __launch_bounds__(512,5) void k_step(
    const __bf16* __restrict__ xst,        // [NP+1][64] slab for step t
    const unsigned* __restrict__ hp_prev,  // [NP+1][64]
    unsigned* __restrict__ hp_cur,
    unsigned* __restrict__ cbufp,          // [NP][64] packed 2xbf16 c
    float* __restrict__ hbuf,              // [NP][128] (written on last step)
    const int* __restrict__ row_ptr, const int* __restrict__ ecol,
    const float* __restrict__ dinv, const __bf16* __restrict__ Wb,
    const float* __restrict__ bi, const float* __restrict__ bf_,
    const float* __restrict__ bo, const float* __restrict__ bg,
    int n, int NP, int last)
{
  __shared__ __align__(16) __bf16 s_a[6*544];
  __shared__ int   s_col[1024];
  __shared__ int   s_deg[16];
  __shared__ int   s_beg[16];
  __shared__ float s_dv[16];
  const int tid=threadIdx.x, wv=tid>>6, l=tid&63;
  const int l15=l&15, quad=l>>4;
  const int v0=blockIdx.x*16;

  if(tid<16){
    int v=v0+tid;
    int beg=(v<n)? row_ptr[v]:0, end=(v<n)? row_ptr[v+1]:0;
    s_beg[tid]=beg; s_deg[tid]=end-beg;
    s_dv[tid]=(v<n)? dinv[v]:0.f;
  }
  __syncthreads();
  for(int idx=tid; idx<1024; idx+=512){
    int m=idx>>6, kk=idx&63;
    s_col[idx]=(kk<s_deg[m])? ecol[s_beg[m]+kk] : NP;   // pad -> zero ghost row
  }
  __syncthreads();

  // ---- phase 1: gather (self + ELL neighbors), 2 nodes per wave ----
  float ax[2], alo[2], ahi[2];
  int K;
  {
    int d0=s_deg[2*wv], d1=s_deg[2*wv+1];
    d0=d0>64?64:d0; d1=d1>64?64:d1;
    K=d0>d1?d0:d1;
  }
  #pragma unroll
  for(int i=0;i<2;++i){
    int v=v0+2*wv+i;
    ax[i]=(float)xst[(size_t)v*64+l];
    unsigned p=hp_prev[(size_t)v*64+l];
    alo[i]=b2f_lo(p); ahi[i]=b2f_hi(p);
  }
  const int* cr=&s_col[(2*wv)*64];
  #pragma unroll 4
  for(int kk=0;kk<K;++kk){
    int u0=cr[kk], u1=cr[64+kk];
    float    x0=(float)xst[(size_t)u0*64+l];
    unsigned p0=hp_prev[(size_t)u0*64+l];
    float    x1=(float)xst[(size_t)u1*64+l];
    unsigned p1=hp_prev[(size_t)u1*64+l];
    ax[0]+=x0; alo[0]+=b2f_lo(p0); ahi[0]+=b2f_hi(p0);
    ax[1]+=x1; alo[1]+=b2f_lo(p1); ahi[1]+=b2f_hi(p1);
  }
  #pragma unroll
  for(int i=0;i<2;++i){              // rare deg>64 overflow
    int m=2*wv+i, d=s_deg[m];
    if(d>64){
      for(int e2=s_beg[m]+64;e2<s_beg[m]+d;++e2){
        int u=ecol[e2];
        ax[i]+=(float)xst[(size_t)u*64+l];
        unsigned p=hp_prev[(size_t)u*64+l];
        alo[i]+=b2f_lo(p); ahi[i]+=b2f_hi(p);
      }
    }
  }
  {
    int kt0=l>>5, q0=(l>>3)&3, j0=l&7;
    int L2=2*l, kt1=2+(L2>>5), q1=(L2>>3)&3, j1=L2&7;
    #pragma unroll
    for(int i=0;i<2;++i){
      int m=2*wv+i; float dv=s_dv[m];
      s_a[kt0*544+q0*136+m*8+j0]=(__bf16)(dv*ax[i]);
      *(unsigned*)&s_a[kt1*544+q1*136+m*8+j1]=f2pk(dv*alo[i],dv*ahi[i]);
    }
  }
  __syncthreads();

  // ---- phase 2: MFMA; wave wv: CT = 8g+wv per gate g ----
  bf16x8 af[6];
  #pragma unroll
  for(int kt=0;kt<6;++kt)
    af[kt]=*(bf16x8*)&s_a[kt*544+quad*136+l15*8];
  const int jg=16*wv+l15;
  floatx4 acc[4];
  {
    #pragma unroll
    for(int g=0;g<4;++g){
      const float* bsel = (g==0)? bi : (g==1)? bf_ : (g==2)? bo : bg;
      float b=bsel[jg];
      floatx4 a={b,b,b,b};
      const __bf16* bp=Wb + (size_t)((8*g+wv)*6)*512 + (size_t)l*8;
      #pragma unroll
      for(int kt=0;kt<6;++kt)
        a=__builtin_amdgcn_mfma_f32_16x16x32_bf16(af[kt],*(const bf16x8*)(bp+kt*512),a,0,0,0);
      acc[g]=a;
    }
  }

  // ---- phase 3: LSTM pointwise; c packed bf16x2 (mirror of hp path) ----
  #pragma unroll
  for(int r=0;r<4;++r){
    int m=quad*4+r, v=v0+m;
    float I=fsig (acc[0][r]);
    float F=fsig (acc[1][r]);
    float O=fsig (acc[2][r]);
    float G=ftanh(acc[3][r]);
    size_t cw=(size_t)v*64+(jg>>1);
    unsigned cold=cbufp[cw];
    float cprev=(l15&1)? b2f_hi(cold) : b2f_lo(cold);
    float cn=F*cprev+I*G;
    float cn2=__shfl_xor(cn,1,64);
    float hn=O*ftanh(cn);
    float hs=s_dv[m]*hn;
    float hs2=__shfl_xor(hs,1,64);
    if((l15&1)==0){
      cbufp[cw]=f2pk(cn,cn2);                      // word w = cols {2w,2w+1}
      hp_cur[(size_t)v*64+(jg>>1)]=f2pk(hs,hs2);
    }
    if(last) hbuf[(size_t)v*128+jg]=hn;
  }
}

// ---------------- head (verified chain) ----------------
__global__ __launch_bounds__(256) void k_head1(const float* __restrict__ h,
    const float* __restrict__ W1t, float* __restrict__ Hio, int n){
  __shared__ float s_h[16][NHID];
  int v0 = blockIdx.x*16;
  for(int i=threadIdx.x; i<16*NHID; i+=256){
    int m = i/NHID, k = i - m*NHID;
    int v = v0 + m;
    s_h[m][k] = (v<n)? h[(size_t)v*NHID + k] : 0.0f;
  }
  __syncthreads();
  int j = threadIdx.x;
  float acc[16];
  #pragma unroll
  for(int m=0;m<16;++m) acc[m]=0.f;
  for(int k=0;k<NHID;++k){
    float w = W1t[k*256 + j];
    #pragma unroll
    for(int m=0;m<16;++m) acc[m] = fmaf(w, s_h[m][k], acc[m]);
  }
  for(int m=0;m<16;++m){
    int v = v0 + m;
    if(v >= n) break;
    Hio[(size_t)v*256 + j] = acc[m];
  }
}
__global__ __launch_bounds__(256) void k_e2n(const float* __restrict__ Hio,
    const int* __restrict__ row_ptr, const int* __restrict__ col,
    const float* __restrict__ b1, float* __restrict__ nodes, int n){
  int wv = threadIdx.x >> 6, lane = threadIdx.x & 63;
  int v = blockIdx.x*4 + wv;
  if(v >= n) return;
  float base0 = Hio[(size_t)v*256 + lane]      + b1[lane];
  float base1 = Hio[(size_t)v*256 + 64 + lane] + b1[64+lane];
  float a0=0.f, a1=0.f;
  int beg=row_ptr[v], end=row_ptr[v+1];
  int e=beg;
  for(; e+1<end; e+=2){          // 2-way unroll: double the loads in flight
    int u0 = col[e], u1 = col[e+1];
    float p0 = Hio[(size_t)u0*256 + 128 + lane];
    float q0 = Hio[(size_t)u0*256 + 192 + lane];
    float p1 = Hio[(size_t)u1*256 + 128 + lane];
    float q1 = Hio[(size_t)u1*256 + 192 + lane];
    a0 += fmaxf(base0 + p0, 0.0f) + fmaxf(base0 + p1, 0.0f);
    a1 += fmaxf(base1 + q0, 0.0f) + fmaxf(base1 + q1, 0.0f);
  }
  if(e<end){
    int u = col[e];
    a0 += fmaxf(base0 + Hio[(size_t)u*256 + 128 + lane], 0.0f);
    a1 += fmaxf(base1 + Hio[(size_t)u*256 + 192 + lane], 0.0f);
  }
  nodes[(size_t)v*NHID + lane]      = a0;
  nodes[(size_t)v*NHID + 64 + lane] = a1;
}
__global__ __launch_bounds__(64) void k_head2(const float* __restrict__ nodes,
    const float* __restrict__ Wct, float* __restrict__ tmp, int n){
  __shared__ float s_n[16][NHID];
  int v0 = blockIdx.x*16;
  for(int i=threadIdx.x; i<16*NHID; i+=64){
    int m = i/NHID, k = i - m*NHID;
    int v = v0 + m;
    s_n[m][k] = (v<n)? nodes[(size_t)v*NHID + k] : 0.0f;
  }
  __syncthreads();
  int j = threadIdx.x;
  float acc[16];
  #pragma unroll
  for(int m=0;m<16;++m) acc[m]=0.f;
  for(int k=0;k<NHID;++k){
    float w = Wct[k*64 + j];
    #pragma unroll
    for(int m=0;m<16;++m) acc[m] = fmaf(w, s_n[m][k], acc[m]);
  }
  for(int m=0;m<16;++m){
    int v = v0 + m;
    if(v >= n) break;
    tmp[(size_t)v*64 + j] = acc[m];
  }
}
__global__ __launch_bounds__(256) void k_final(const float* __restrict__ tmp,
    const int* __restrict__ row_ptr, const int* __restrict__ col,
    const float* __restrict__ dinv, const float* __restrict__ bc,
    float* __restrict__ out, int n){
  int wv = threadIdx.x >> 6, lane = threadIdx.x & 63;
  int v = blockIdx.x*4 + wv;
  if(v >= n) return;
  float dv = dinv[v];
  float acc = dv*dv*tmp[(size_t)v*64 + lane];
  int beg=row_ptr[v], end=row_ptr[v+1];
  int e=beg;
  for(; e+1<end; e+=2){          // 2-way unroll
    int u0 = col[e], u1 = col[e+1];
    float d0 = dinv[u0], d1 = dinv[u1];
    float t0 = tmp[(size_t)u0*64 + lane];
    float t1 = tmp[(size_t)u1*64 + lane];
    acc = fmaf(dv*d0, t0, acc);
    acc = fmaf(dv*d1, t1, acc);
  }
  if(e<end){
    int u = col[e];
    acc = fmaf(dv*dinv[u], tmp[(size_t)u*64 + lane], acc);
  }
  out[(size_t)v*64 + lane] = acc + bc[lane];
}

extern "C" void kernel_launch(void* const* d_in, const int* in_sizes, int n_in,
                              void* d_out, int out_size, void* d_ws, size_t ws_size,
                              hipStream_t stream) {
  (void)n_in; (void)ws_size;
  const float* x  = (const float*)d_in[0];
  const int*   ei = (const int*)d_in[1];
  const float* Wi = (const float*)d_in[4];  const float* bi  = (const float*)d_in[5];
  const float* Wf = (const float*)d_in[6];  const float* bf_ = (const float*)d_in[7];
  const float* Wo = (const float*)d_in[8];  const float* bo  = (const float*)d_in[9];
  const float* Wg = (const float*)d_in[10]; const float* bg  = (const float*)d_in[11];
  const float* W1 = (const float*)d_in[12]; const float* b1  = (const float*)d_in[13];
  const float* Wc = (const float*)d_in[14]; const float* bc  = (const float*)d_in[15];
  float* out = (float*)d_out;

  const int E = in_sizes[2];
  const int n = out_size / NOUT;
  const int T = in_sizes[0] / (n * NIN);
  const int ntiles = (n + 15)/16;
  const int NP = ntiles*16;
  const int* srcl = ei;
  const int* dstl = ei + E;

  char* p = (char*)d_ws;
  auto alloc = [&](size_t bytes){ char* r = p; p += ((bytes + 255)/256)*256; return r; };
  int*      deg     = (int*)     alloc((size_t)n*4);
  float*    dinv    = (float*)   alloc((size_t)n*4);
  int*      row_ptr = (int*)     alloc((size_t)(n+1)*4);
  int*      fill    = (int*)     alloc((size_t)n*4);
  int*      ecol    = (int*)     alloc((size_t)E*4);
  __bf16*   Wb      = (__bf16*)  alloc((size_t)32*6*64*8*2);
  float*    W1t     = (float*)   alloc((size_t)128*256*4);
  float*    Wct     = (float*)   alloc((size_t)128*64*4);
  __bf16*   xs      = (__bf16*)  alloc((size_t)T*(NP+1)*64*2);
  unsigned* hpA     = (unsigned*)alloc((size_t)(NP+1)*64*4);
  unsigned* hpB     = (unsigned*)alloc((size_t)(NP+1)*64*4);
  unsigned* cbufp   = (unsigned*)alloc((size_t)NP*64*4);
  float*    hbuf    = (float*)   alloc((size_t)NP*128*4);
  float*    Hio     = (float*)   alloc((size_t)NP*256*4);
  float*    nodes   = (float*)   alloc((size_t)n*NHID*4);
  float*    tmp     = (float*)   alloc((size_t)NP*64*4);

  int gn = (n+255)/256;
  int gE = (E+255)/256;

  k_deg_init <<<gn, 256, 0, stream>>>(deg, n);
  k_deg_count<<<gE, 256, 0, stream>>>(dstl, E, deg);
  k_dinv     <<<gn, 256, 0, stream>>>(deg, dinv, n);
  k_scan     <<<1, 1024, 0, stream>>>(deg, row_ptr, fill, n);
  k_fill     <<<gE, 256, 0, stream>>>(srcl, dstl, E, fill, ecol);

  k_prep_wb<<<(32*6*64*8+255)/256, 256, 0, stream>>>(Wi, Wf, Wo, Wg, Wb);
  k_prep_w1<<<(128*256+255)/256, 256, 0, stream>>>(W1, W1t);
  k_prep_wc<<<(128*64+255)/256, 256, 0, stream>>>(Wc, Wct);

  k_init<<<(((NP+1)*64)+255)/256, 256, 0, stream>>>(hpA, hpB, cbufp, xs, NP, T);
  k_xscale<<<dim3((n*8+255)/256, T), 256, 0, stream>>>(x, dinv, xs, n, NP);

  for(int t=0; t<T; ++t){
    const __bf16* xst = xs + (size_t)t*(size_t)(NP+1)*64;
    const unsigned* hp = (t & 1)? hpB : hpA;
    unsigned*       hc = (t & 1)? hpA : hpB;
    k_step<<<ntiles, 512, 0, stream>>>(xst, hp, hc, cbufp, hbuf, row_ptr, ecol, dinv,
                                       Wb, bi, bf_, bo, bg, n, NP, (t==T-1)?1:0);
  }

  k_head1<<<ntiles, 256, 0, stream>>>(hbuf, W1t, Hio, n);
  k_e2n  <<<(n+3)/4, 256, 0, stream>>>(Hio, row_ptr, ecol, b1, nodes, n);
  k_head2<<<(n+15)/16, 64, 0, stream>>>(nodes, Wct, tmp, n);
  k_final<<<(n+3)/4, 256, 0, stream>>>(tmp, row_ptr, ecol, dinv, bc, out, n);
}